// Round 8
// baseline (188.897 us; speedup 1.0000x reference)
//
#include <hip/hip_runtime.h>
#include <hip/hip_bf16.h>

#define IMG_H 512
#define IMG_W 512
#define IMG_N (IMG_H * IMG_W)
#define NPLANES 48          // 16 batch * 3 channels
#define TILE 64             // 64x64 output tile per block
#define XS 88               // LDS row stride (elements); rows 16B-aligned
#define SSIM_C1 0.0001f
#define SSIM_C2 0.0009f

typedef __attribute__((ext_vector_type(8))) short bf16x8;   // 8 bf16 = 4 VGPR
typedef __attribute__((ext_vector_type(4))) float f32x4;

// RNE float->bf16 (bits) — exact, used only for the 11 weight taps
__device__ __forceinline__ unsigned bf16r(float x) {
    unsigned u = __float_as_uint(x);
    return (u + 0x7fffu + ((u >> 16) & 1u)) >> 16;
}
// Fast pack: round-half-up to bf16, 3 VALU ops (add, add, v_perm_b32).
// a -> low half, b -> high half.
__device__ __forceinline__ unsigned pk2(float a, float b) {
    const unsigned ua = __float_as_uint(a) + 0x8000u;
    const unsigned ub = __float_as_uint(b) + 0x8000u;
    return __builtin_amdgcn_perm(ub, ua, 0x07060302u);
}
__device__ __forceinline__ float lo16(unsigned u) { return __uint_as_float(u << 16); }
__device__ __forceinline__ float hi16(unsigned u) { return __uint_as_float(u & 0xffff0000u); }
__device__ __forceinline__ unsigned sqpk(unsigned u) {
    float a = lo16(u), b = hi16(u); return pk2(a * a, b * b);
}
__device__ __forceinline__ unsigned mulpk(unsigned u, unsigned v) {
    return pk2(lo16(u) * lo16(v), hi16(u) * hi16(v));
}

// Separable 11x11 Gaussian conv via MFMA. Per block: 64x64 outputs.
// Stage X rows/cols [base-8, base+71] as bf16 (p,t). Per channel (p,t,p2,t2,pt):
//   H-pass: D[16r x 16c] = X * Wh  (Wh[k][j] = g[k-j-3], banded, in registers)
//   store H transposed (C-layout rows are contiguous) -> Ht[col][hrow]
//   V-pass: D = Wv * Ht-frag (Wv = same register fragment), accumulate in VGPRs.
// Each wave owns 16 output cols end-to-end => no barriers in the channel loop.
__global__ __launch_bounds__(256) void ssim_mfma_kernel(
    const float* __restrict__ pred, const float* __restrict__ target,
    const float* __restrict__ window, float* __restrict__ partial)
{
    __shared__ unsigned short Xp[80 * XS];   // 14080 B
    __shared__ unsigned short Xt[80 * XS];   // 14080 B
    __shared__ unsigned short Ht[64 * XS];   // 11264 B
    __shared__ unsigned short gbfS[16];      // bf16 taps, [11..15] = 0
    __shared__ float wsum[4];

    const int tid  = threadIdx.x;
    const int w    = tid >> 6;       // wave = col-tile (16 cols)
    const int lane = tid & 63;
    const int n15  = lane & 15;
    const int quad = lane >> 4;

    // bf16 tap table: g[i] = row sums of the normalized 2D window
    if (tid < 16) {
        float gv = 0.f;
        if (tid < 11) {
            float s = 0.f;
            #pragma unroll
            for (int j = 0; j < 11; ++j) s += window[tid * 11 + j];
            gv = s;
        }
        gbfS[tid] = (unsigned short)bf16r(gv);
    }

    const int plane  = blockIdx.z;
    const int base_r = blockIdx.y * TILE;
    const int base_c = blockIdx.x * TILE;
    const float* pp = pred   + (size_t)plane * IMG_N;
    const float* tp = target + (size_t)plane * IMG_N;

    // ---- Stage p,t as bf16: rows/cols [base-8, base+71], zero outside ----
    #pragma unroll
    for (int i = 0; i < 7; ++i) {
        const unsigned fi = (unsigned)tid + 256u * i;   // 80 rows x 20 float4
        if (fi < 1600u) {
            const unsigned ri = fi / 20u, q = fi - 20u * ri;
            const int gr = base_r - 8 + (int)ri;
            const int gc = base_c - 8 + 4 * (int)q;
            const bool ok = ((unsigned)gr < (unsigned)IMG_H) &&
                            ((unsigned)gc < (unsigned)IMG_W);
            const float4 z4 = make_float4(0.f, 0.f, 0.f, 0.f);
            float4 p4 = ok ? *(const float4*)(pp + gr * IMG_W + gc) : z4;
            float4 t4 = ok ? *(const float4*)(tp + gr * IMG_W + gc) : z4;
            const int off = (int)ri * XS + 4 * (int)q;   // 8B-aligned
            *(uint2*)&Xp[off] = make_uint2(pk2(p4.x, p4.y), pk2(p4.z, p4.w));
            *(uint2*)&Xt[off] = make_uint2(pk2(t4.x, t4.y), pk2(t4.z, t4.w));
        }
    }
    __syncthreads();

    // ---- Weight fragment: element j holds g[8*quad + j - n15 - 3] (or 0).
    // Serves as B-operand (Wh[k][n]) in H-pass and A-operand (Wv[m][k]) in V.
    uint4 wu;
    {
        unsigned wd[4];
        #pragma unroll
        for (int d = 0; d < 4; ++d) {
            const int t0 = 8 * quad + 2 * d - n15 - 3;
            const unsigned lo = gbfS[((unsigned)t0       <= 10u) ? t0       : 11];
            const unsigned hi = gbfS[((unsigned)(t0 + 1) <= 10u) ? (t0 + 1) : 11];
            wd[d] = lo | (hi << 16);
        }
        wu = make_uint4(wd[0], wd[1], wd[2], wd[3]);
    }
    const bf16x8 wfrag = __builtin_bit_cast(bf16x8, wu);
    const f32x4 zero4 = {0.f, 0.f, 0.f, 0.f};

    // ---- Hoist all X fragments into registers: 10 x b128, loaded once ----
    uint4 pu[5], tu[5];
    #pragma unroll
    for (int rt = 0; rt < 5; ++rt) {
        const int xoff = (16 * rt + n15) * XS + 16 * w + 8 * quad;  // 16B-al
        pu[rt] = *(const uint4*)&Xp[xoff];
        tu[rt] = *(const uint4*)&Xt[xoff];
    }

    f32x4 vacc[5][4];
    #pragma unroll
    for (int c = 0; c < 5; ++c)
        #pragma unroll
        for (int r = 0; r < 4; ++r) vacc[c][r] = zero4;

    #pragma unroll
    for (int ch = 0; ch < 5; ++ch) {
        // ---- H-pass: 5 row-tiles cover H rows [base_r-8, base_r+71] ----
        #pragma unroll
        for (int rt = 0; rt < 5; ++rt) {
            uint4 au;
            if      (ch == 0) au = pu[rt];
            else if (ch == 1) au = tu[rt];
            else if (ch == 2) au = make_uint4(sqpk(pu[rt].x), sqpk(pu[rt].y),
                                              sqpk(pu[rt].z), sqpk(pu[rt].w));
            else if (ch == 3) au = make_uint4(sqpk(tu[rt].x), sqpk(tu[rt].y),
                                              sqpk(tu[rt].z), sqpk(tu[rt].w));
            else              au = make_uint4(mulpk(pu[rt].x, tu[rt].x),
                                              mulpk(pu[rt].y, tu[rt].y),
                                              mulpk(pu[rt].z, tu[rt].z),
                                              mulpk(pu[rt].w, tu[rt].w));
            const bf16x8 afrag = __builtin_bit_cast(bf16x8, au);
            const f32x4 hd = __builtin_amdgcn_mfma_f32_16x16x32_bf16(
                afrag, wfrag, zero4, 0, 0, 0);
            // C-layout: row = 4*quad+reg, col = n15 -> transposed store is b64
            *(uint2*)&Ht[(16 * w + n15) * XS + 16 * rt + 4 * quad] =
                make_uint2(pk2(hd[0], hd[1]), pk2(hd[2], hd[3]));
        }
        // same-wave RAW through LDS: compiler inserts lgkmcnt waits
        // ---- V-pass: 4 output row-tiles, accumulate in registers ----
        #pragma unroll
        for (int rt = 0; rt < 4; ++rt) {
            const bf16x8 bfrag = *(const bf16x8*)&Ht[(16 * w + n15) * XS +
                                                     16 * rt + 8 * quad];
            vacc[ch][rt] = __builtin_amdgcn_mfma_f32_16x16x32_bf16(
                wfrag, bfrag, vacc[ch][rt], 0, 0, 0);
        }
    }

    // ---- SSIM epilogue: 16 pixels per lane ----
    float acc = 0.f;
    #pragma unroll
    for (int rt = 0; rt < 4; ++rt) {
        #pragma unroll
        for (int r = 0; r < 4; ++r) {
            const float mu1 = vacc[0][rt][r], mu2 = vacc[1][rt][r];
            const float e11 = vacc[2][rt][r], e22 = vacc[3][rt][r];
            const float e12 = vacc[4][rt][r];
            const float mu1_sq = mu1 * mu1, mu2_sq = mu2 * mu2;
            const float mu1_mu2 = mu1 * mu2;
            const float s1  = e11 - mu1_sq;
            const float s2  = e22 - mu2_sq;
            const float s12 = e12 - mu1_mu2;
            const float num = (2.f * mu1_mu2 + SSIM_C1) * (2.f * s12 + SSIM_C2);
            const float den = (mu1_sq + mu2_sq + SSIM_C1) * (s1 + s2 + SSIM_C2);
            acc += num * __builtin_amdgcn_rcpf(den);
        }
    }

    // ---- Block reduction ----
    #pragma unroll
    for (int off = 32; off > 0; off >>= 1)
        acc += __shfl_down(acc, off, 64);
    if (lane == 0) wsum[w] = acc;
    __syncthreads();
    if (tid == 0) {
        const int bid = blockIdx.x + gridDim.x * (blockIdx.y + gridDim.y * blockIdx.z);
        partial[bid] = wsum[0] + wsum[1] + wsum[2] + wsum[3];
    }
}

// Reduce 3072 partials -> scalar (double accumulate)
__global__ __launch_bounds__(256) void ssim_reduce_kernel(
    const float* __restrict__ partial, float* __restrict__ out)
{
    const int tid = threadIdx.x;
    float s = 0.f;
    #pragma unroll
    for (int k = 0; k < 12; ++k) s += partial[tid + 256 * k];
    double acc = (double)s;
    #pragma unroll
    for (int off = 32; off > 0; off >>= 1)
        acc += __shfl_down(acc, off, 64);
    __shared__ double wsumd[4];
    const int lane = tid & 63, wid = tid >> 6;
    if (lane == 0) wsumd[wid] = acc;
    __syncthreads();
    if (tid == 0) {
        const double total = wsumd[0] + wsumd[1] + wsumd[2] + wsumd[3];
        const double N = (double)NPLANES * IMG_H * IMG_W;
        out[0] = (float)(1.0 - total / N);
    }
}

extern "C" void kernel_launch(void* const* d_in, const int* in_sizes, int n_in,
                              void* d_out, int out_size, void* d_ws, size_t ws_size,
                              hipStream_t stream)
{
    const float* pred   = (const float*)d_in[0];
    const float* target = (const float*)d_in[1];
    const float* window = (const float*)d_in[2];
    float* out = (float*)d_out;
    float* partial = (float*)d_ws;   // 3072 floats = 12 KiB

    dim3 grid(IMG_W / TILE, IMG_H / TILE, NPLANES);   // (8, 8, 48) = 3072 blocks
    ssim_mfma_kernel<<<grid, 256, 0, stream>>>(pred, target, window, partial);
    ssim_reduce_kernel<<<1, 256, 0, stream>>>(partial, out);
}